// Round 6
// baseline (424.281 us; speedup 1.0000x reference)
//
#include <hip/hip_runtime.h>
#include <hip/hip_bf16.h>

#define NROWS 16384
#define DIN   256
#define DH    128
#define SPLITS 4
#define KVSPL  4096              // NROWS / SPLITS
#define KVBLK  32
#define NIT    (KVSPL / KVBLK)   // 128
#define QBLK   256               // q rows per attn block (4 waves x 64)

typedef __attribute__((ext_vector_type(8)))  short  short8;   // 8 bf16 = 16B
typedef __attribute__((ext_vector_type(4)))  float  f32x4;
typedef __attribute__((ext_vector_type(16))) float  f32x16;
typedef __attribute__((ext_vector_type(4)))  unsigned short u16x4;
typedef __attribute__((ext_vector_type(4)))  unsigned int   u32x4;

__device__ __forceinline__ unsigned short f2bf(float f) {
  unsigned int u = __float_as_uint(f);
  unsigned int r = (u + 0x7FFFu + ((u >> 16) & 1u)) >> 16;  // RNE
  return (unsigned short)r;
}
__device__ __forceinline__ float bf2f(unsigned short b) {
  return __uint_as_float(((unsigned int)b) << 16);
}

// async global->LDS, 16B per lane; dst = wave-uniform base + lane*16
__device__ __forceinline__ void gload_lds16(const void* g, void* l) {
  __builtin_amdgcn_global_load_lds(
      (const __attribute__((address_space(1))) unsigned int*)g,
      (__attribute__((address_space(3))) unsigned int*)l, 16, 0, 0);
}

// ---------------------------------------------------------------------------
// Kernel 0: W [256][128] f32 -> W^T [128][256] bf16
// ---------------------------------------------------------------------------
__global__ void prep_w(const float* __restrict__ Wq, const float* __restrict__ Wk,
                       unsigned short* __restrict__ WqT, unsigned short* __restrict__ WkT) {
  const float* W = blockIdx.x ? Wk : Wq;
  unsigned short* WT = blockIdx.x ? WkT : WqT;
  int c = threadIdx.x;  // 0..127
  for (int k = 0; k < DIN; ++k)
    WT[c * DIN + k] = f2bf(W[k * DH + c]);
}

// ---------------------------------------------------------------------------
// Kernel 1: per 64-row H tile (256 blocks x 256 thr):
//   H^T -> HbT bf16 (128B-contiguous chunks); Q = (H@Wq+bq)*SCALE*LOG2E;
//   K = H@Wk+bk (bf16)
// ---------------------------------------------------------------------------
__global__ __launch_bounds__(256) void prep_hqk(
    const float* __restrict__ H,
    const unsigned short* __restrict__ WqT, const float* __restrict__ bq,
    const unsigned short* __restrict__ WkT, const float* __restrict__ bk,
    unsigned short* __restrict__ HbT,
    unsigned short* __restrict__ Qb, unsigned short* __restrict__ Kb) {
  __shared__ __align__(16) unsigned short tile[64][264];
  const int tid = threadIdx.x;
  const int qbase = blockIdx.x * 64;

  for (int i = tid; i < 64 * 64; i += 256) {
    int r = i >> 6, c4 = i & 63;
    const f32x4 v = *reinterpret_cast<const f32x4*>(H + (size_t)(qbase + r) * DIN + c4 * 4);
    u16x4 b;
    b[0] = f2bf(v[0]); b[1] = f2bf(v[1]); b[2] = f2bf(v[2]); b[3] = f2bf(v[3]);
    *reinterpret_cast<u16x4*>(&tile[r][c4 * 4]) = b;
  }
  __syncthreads();

  // transposed write: lanes 0..7 cover seg 0..7 -> 128B contiguous per c-row
  for (int i = tid; i < 256 * 8; i += 256) {
    int c = i >> 3, seg = i & 7;
    short8 t;
#pragma unroll
    for (int j = 0; j < 8; ++j) t[j] = (short)tile[seg * 8 + j][c];
    *reinterpret_cast<short8*>(HbT + (size_t)c * NROWS + qbase + seg * 8) = t;
  }

  const int lane = tid & 63, w = tid >> 6;
  const int col = lane & 15, grp = lane >> 4;

  short8 ah[8];
#pragma unroll
  for (int c = 0; c < 8; ++c)
    ah[c] = *reinterpret_cast<const short8*>(&tile[w * 16 + col][c * 32 + grp * 8]);

  f32x4 accq[8], acck[8];
#pragma unroll
  for (int ct = 0; ct < 8; ++ct) { accq[ct] = f32x4{0,0,0,0}; acck[ct] = f32x4{0,0,0,0}; }

#pragma unroll
  for (int ct = 0; ct < 8; ++ct) {
#pragma unroll
    for (int c = 0; c < 8; ++c) {
      short8 bwq = *reinterpret_cast<const short8*>(WqT + (size_t)(ct * 16 + col) * DIN + c * 32 + grp * 8);
      accq[ct] = __builtin_amdgcn_mfma_f32_16x16x32_bf16(ah[c], bwq, accq[ct], 0, 0, 0);
      short8 bwk = *reinterpret_cast<const short8*>(WkT + (size_t)(ct * 16 + col) * DIN + c * 32 + grp * 8);
      acck[ct] = __builtin_amdgcn_mfma_f32_16x16x32_bf16(ah[c], bwk, acck[ct], 0, 0, 0);
    }
  }

  const float QSCALE = 0.12751742f;  // (1/sqrt(128)) * log2(e)
#pragma unroll
  for (int ct = 0; ct < 8; ++ct) {
    float vbq = bq[ct * 16 + col];
    float vbk = bk[ct * 16 + col];
#pragma unroll
    for (int r = 0; r < 4; ++r) {
      int row = qbase + w * 16 + grp * 4 + r;
      Qb[(size_t)row * DH + ct * 16 + col] = f2bf((accq[ct][r] + vbq) * QSCALE);
      Kb[(size_t)row * DH + ct * 16 + col] = f2bf(acck[ct][r] + vbk);
    }
  }
}

// ---------------------------------------------------------------------------
// Kernel 2: flash attention, m=0 softmax, 4-way kv-split x 2-way d-split.
// grid 512: sp = bid&3, dh = (bid>>2)&1 (both fixed per XCD), qb = bid>>3.
// Block = 256 thr = 4 waves; wave owns 64 q-rows (2 q-groups) x 128 d-cols.
// KVBLK=32; K [32][256B] + V [128][64B] double-buffered via global_load_lds
// (XOR-pre-swizzled source), prefetch 1 tile ahead, counted vmcnt(4).
// Each K-frag / V-frag LDS read feeds 2 MFMAs (both q-groups): 16 reads /
// 32 MFMA per wave-iter. Raw (unnormalized) O partials + row-sums out.
// ---------------------------------------------------------------------------
__global__ __launch_bounds__(256, 2) void attn_fa(
    const unsigned short* __restrict__ Qb, const unsigned short* __restrict__ Kb,
    const unsigned short* __restrict__ HbT,
    unsigned short* __restrict__ Opart, float* __restrict__ Lp) {
  __shared__ __align__(16) char lds[32768];
  char* KtC = lds;            // 2 x [32][256B]
  char* VtC = lds + 16384;    // 2 x [128][64B]

  const int tid = threadIdx.x;
  const int lane = tid & 63, w = tid >> 6;       // w in 0..3
  const int l31 = lane & 31, hi = lane >> 5;
  const int kswz = (l31 & 7) << 4;
  const int vswz = ((l31 >> 1) & 3) << 4;
  const int dlv = l31 - 4 * hi;

  const int sp = blockIdx.x & 3;
  const int dh = (blockIdx.x >> 2) & 1;
  const int qb = blockIdx.x >> 3;                // 0..63
  const int qrow0 = qb * QBLK + w * 64;
  const int kv0 = sp * KVSPL;

  // staging lane constants (source pre-swizzled; reads apply same XOR)
  int krow[2], kcol[2];
#pragma unroll
  for (int s = 0; s < 2; ++s) {
    int kv = w * 8 + s * 4 + (lane >> 4);
    krow[s] = kv;
    kcol[s] = (((lane & 15) * 16) ^ ((kv & 7) << 4)) >> 1;   // element offset
  }
  int vrow[2], vcol[2];
#pragma unroll
  for (int s = 0; s < 2; ++s) {
    int d = w * 32 + s * 16 + (lane >> 2);
    vrow[s] = dh * 128 + d;
    vcol[s] = (((lane & 3) * 16) ^ (((d >> 1) & 3) << 4)) >> 1;
  }

  // Q B-frags (pre-scaled): lane n=q=l31(+32), k = c*16 + hi*8 + j
  short8 qfa[8], qfb[8];
#pragma unroll
  for (int c = 0; c < 8; ++c) {
    qfa[c] = *reinterpret_cast<const short8*>(Qb + (size_t)(qrow0 + l31) * DH + c * 16 + hi * 8);
    qfb[c] = *reinterpret_cast<const short8*>(Qb + (size_t)(qrow0 + 32 + l31) * DH + c * 16 + hi * 8);
  }

  f32x16 acc[2][4];
#pragma unroll
  for (int g = 0; g < 2; ++g)
#pragma unroll
    for (int dt = 0; dt < 4; ++dt) acc[g][dt] = {};
  float lsa = 0.f, lsb = 0.f;

  // prologue: stage tile 0 into buf 0
#pragma unroll
  for (int s = 0; s < 2; ++s)
    gload_lds16(Kb + (size_t)(kv0 + krow[s]) * DH + kcol[s], KtC + w * 2048 + s * 1024);
#pragma unroll
  for (int s = 0; s < 2; ++s)
    gload_lds16(HbT + (size_t)vrow[s] * NROWS + kv0 + vcol[s], VtC + w * 2048 + s * 1024);

  for (int it = 0; it < NIT; ++it) {
    const int buf = it & 1;
    const int kvbase = kv0 + it * KVBLK;
    const int kvnext = kvbase + KVBLK;
    char* Kwr = KtC + (buf ^ 1) * 8192;
    char* Vwr = VtC + (buf ^ 1) * 8192;

    // 1. issue next-tile stage (last iter reads harmless in-ws OOB)
#pragma unroll
    for (int s = 0; s < 2; ++s)
      gload_lds16(Kb + (size_t)(kvnext + krow[s]) * DH + kcol[s], Kwr + w * 2048 + s * 1024);
#pragma unroll
    for (int s = 0; s < 2; ++s)
      gload_lds16(HbT + (size_t)vrow[s] * NROWS + kvnext + vcol[s], Vwr + w * 2048 + s * 1024);

    // 2. wait current tile (4 prefetch loads stay in flight)
    asm volatile("s_waitcnt vmcnt(4)" ::: "memory");
    __builtin_amdgcn_s_barrier();
    __builtin_amdgcn_sched_barrier(0);

    // 3. swapped QK^T: p[kv][q]; A = K (LDS, shared by both q-groups), B = Q
    const char* Krd = KtC + buf * 8192;
    f32x16 pa = {}, pb = {};
    __builtin_amdgcn_s_setprio(1);
#pragma unroll
    for (int c = 0; c < 8; ++c) {
      short8 ka = *reinterpret_cast<const short8*>(Krd + l31 * 256 + ((c * 32 + hi * 16) ^ kswz));
      pa = __builtin_amdgcn_mfma_f32_32x32x16_bf16(ka, qfa[c], pa, 0, 0, 0);
      pb = __builtin_amdgcn_mfma_f32_32x32x16_bf16(ka, qfb[c], pb, 0, 0, 0);
    }
    __builtin_amdgcn_s_setprio(0);

    // 4. diag zero (logit 0 pre-scale -> p=1 after exp2)
    if (qrow0 == kvbase) {
#pragma unroll
      for (int r = 0; r < 16; ++r)
        if (dlv == ((r & 3) + 8 * (r >> 2))) pa[r] = 0.f;
    }
    if (qrow0 + 32 == kvbase) {
#pragma unroll
      for (int r = 0; r < 16; ++r)
        if (dlv == ((r & 3) + 8 * (r >> 2))) pb[r] = 0.f;
    }

    // 5. exp2 + lane-local row-sums
#pragma unroll
    for (int r = 0; r < 16; ++r) { pa[r] = exp2f(pa[r]); lsa += pa[r]; }
#pragma unroll
    for (int r = 0; r < 16; ++r) { pb[r] = exp2f(pb[r]); lsb += pb[r]; }

    // 6. P -> bf16 A-frags: 8+8 cvt_pk, 4+4 permlane32_swap (dst = low word)
    unsigned int Wa[8], Wb[8];
#pragma unroll
    for (int j = 0; j < 8; ++j) {
      asm("v_cvt_pk_bf16_f32 %0, %1, %2" : "=v"(Wa[j]) : "v"(pa[2*j]), "v"(pa[2*j+1]));
      asm("v_cvt_pk_bf16_f32 %0, %1, %2" : "=v"(Wb[j]) : "v"(pb[2*j]), "v"(pb[2*j+1]));
    }
#pragma unroll
    for (int b = 0; b < 2; ++b) {
      asm("v_permlane32_swap_b32 %0, %1" : "+v"(Wa[b*4+0]), "+v"(Wa[b*4+2]));
      asm("v_permlane32_swap_b32 %0, %1" : "+v"(Wa[b*4+1]), "+v"(Wa[b*4+3]));
      asm("v_permlane32_swap_b32 %0, %1" : "+v"(Wb[b*4+0]), "+v"(Wb[b*4+2]));
      asm("v_permlane32_swap_b32 %0, %1" : "+v"(Wb[b*4+1]), "+v"(Wb[b*4+3]));
    }

    // 7. PV: V-frag read once, feeds both q-groups
    const char* Vrd = VtC + buf * 8192;
    __builtin_amdgcn_s_setprio(1);
#pragma unroll
    for (int kc = 0; kc < 2; ++kc) {
      u32x4 wa = { Wa[kc*4+0], Wa[kc*4+1], Wa[kc*4+2], Wa[kc*4+3] };
      u32x4 wb = { Wb[kc*4+0], Wb[kc*4+1], Wb[kc*4+2], Wb[kc*4+3] };
      short8 paf = __builtin_bit_cast(short8, wa);
      short8 pbf = __builtin_bit_cast(short8, wb);
      const int off = (kc * 32 + hi * 16) ^ vswz;
#pragma unroll
      for (int dt = 0; dt < 4; ++dt) {
        short8 bv = *reinterpret_cast<const short8*>(Vrd + (dt * 32 + l31) * 64 + off);
        acc[0][dt] = __builtin_amdgcn_mfma_f32_32x32x16_bf16(paf, bv, acc[0][dt], 0, 0, 0);
        acc[1][dt] = __builtin_amdgcn_mfma_f32_32x32x16_bf16(pbf, bv, acc[1][dt], 0, 0, 0);
      }
    }
    __builtin_amdgcn_s_setprio(0);

    // 8. end-of-iter barrier: all reads of buf done before next overwrite
    __builtin_amdgcn_sched_barrier(0);
    __builtin_amdgcn_s_barrier();
  }

  // ---- epilogue: raw O partials (bf16) + row sums ----
  lsa += __shfl_xor(lsa, 32);
  lsb += __shfl_xor(lsb, 32);

  const size_t obase = (size_t)sp * NROWS * DIN;
  const int colb = dh * 128;
#pragma unroll
  for (int dt = 0; dt < 4; ++dt) {
#pragma unroll
    for (int r = 0; r < 16; ++r) {
      int q = qrow0 + (r & 3) + 8 * (r >> 2) + 4 * hi;
      int cc = colb + dt * 32 + l31;
      Opart[obase + (size_t)q * DIN + cc] = f2bf(acc[0][dt][r]);
      Opart[obase + (size_t)(q + 32) * DIN + cc] = f2bf(acc[1][dt][r]);
    }
  }
  if (dh == 0 && lane < 32) {
    Lp[(size_t)sp * NROWS + qrow0 + l31] = lsa;
    Lp[(size_t)sp * NROWS + qrow0 + 32 + l31] = lsb;
  }
}

// ---------------------------------------------------------------------------
// Kernel 3: merge 4 raw partials (out = (Sum O_s)/(Sum l_s) + H).
// ---------------------------------------------------------------------------
__global__ __launch_bounds__(256) void merge_split(
    const unsigned short* __restrict__ Opart, const float* __restrict__ Lp,
    const float* __restrict__ H, float* __restrict__ out) {
  const int row = blockIdx.x * 16 + (threadIdx.x >> 4);
  const int d0 = (threadIdx.x & 15) * 16;

  float Wt = 0.f;
#pragma unroll
  for (int s = 0; s < SPLITS; ++s) Wt += Lp[(size_t)s * NROWS + row];
  float invW = 1.0f / Wt;

  float acc[16];
#pragma unroll
  for (int j = 0; j < 16; ++j) acc[j] = 0.f;
#pragma unroll
  for (int s = 0; s < SPLITS; ++s) {
    const unsigned short* p = Opart + ((size_t)s * NROWS + row) * DIN + d0;
#pragma unroll
    for (int h = 0; h < 2; ++h) {
      short8 v = *reinterpret_cast<const short8*>(p + h * 8);
#pragma unroll
      for (int j = 0; j < 8; ++j) acc[h * 8 + j] += bf2f((unsigned short)v[j]);
    }
  }
  const float* hrow = H + (size_t)row * DIN + d0;
  float* orow = out + (size_t)row * DIN + d0;
#pragma unroll
  for (int q = 0; q < 4; ++q) {
    f32x4 hv = *reinterpret_cast<const f32x4*>(hrow + q * 4);
    f32x4 ov;
#pragma unroll
    for (int j = 0; j < 4; ++j) ov[j] = acc[q * 4 + j] * invW + hv[j];
    *reinterpret_cast<f32x4*>(orow + q * 4) = ov;
  }
}

// ---------------------------------------------------------------------------
extern "C" void kernel_launch(void* const* d_in, const int* in_sizes, int n_in,
                              void* d_out, int out_size, void* d_ws, size_t ws_size,
                              hipStream_t stream) {
  const float* H  = (const float*)d_in[0];
  const float* Wq = (const float*)d_in[1];
  const float* bq = (const float*)d_in[2];
  const float* Wk = (const float*)d_in[3];
  const float* bk = (const float*)d_in[4];
  float* out = (float*)d_out;

  char* ws = (char*)d_ws;
  unsigned short* HbT   = (unsigned short*)(ws);                    // 8 MB
  unsigned short* Qb    = (unsigned short*)(ws + 8388608);          // 4 MB
  unsigned short* Kb    = (unsigned short*)(ws + 12582912);         // 4 MB
  unsigned short* WqT   = (unsigned short*)(ws + 16777216);         // 64 KB
  unsigned short* WkT   = (unsigned short*)(ws + 16842752);         // 64 KB
  unsigned short* Opart = (unsigned short*)(ws + 20971520);         // 32 MB
  float*          Lp    = (float*)(ws + 54525952);                  // 256 KB

  prep_w<<<2, 128, 0, stream>>>(Wq, Wk, WqT, WkT);
  prep_hqk<<<256, 256, 0, stream>>>(H, WqT, bq, WkT, bk, HbT, Qb, Kb);
  attn_fa<<<512, 256, 0, stream>>>(Qb, Kb, HbT, Opart, Lp);
  merge_split<<<1024, 256, 0, stream>>>(Opart, Lp, H, out);
}